// Round 11
// baseline (80.718 us; speedup 1.0000x reference)
//
#include <hip/hip_runtime.h>

#define NB 4
#define LB 512
#define DB 1024
#define PB 768
#define NBINS 64
#define LEN_KEEP 128          // int(512 * (1 - 0.75))
#define EPSL 1e-19f
#define WIN 3                 // excluded buckets are >=3.5 spacings away:
                              // kern <= 2^-22.3 ~ 2e-7; dropped mass ~1e-5
                              // vs per-bin sums O(10) -> ~1e-6 relative

#if defined(__has_builtin)
#if __has_builtin(__builtin_amdgcn_exp2f)
#define HAVE_EXP2 1
#endif
#endif

__device__ __forceinline__ float fast_exp2(float x) {
#ifdef HAVE_EXP2
    return __builtin_amdgcn_exp2f(x);   // raw v_exp_f32
#else
    return __expf(x * 0.69314718055994530942f);
#endif
}

// ---------------------------------------------------------------------------
// K1: min/max partials over img, 64 blocks x 256 threads, float4 loads.
//     64 partials -> entropy prologue reduces them with one wave-shuffle.
// ---------------------------------------------------------------------------
__global__ void minmax_partial(const float4* __restrict__ v,
                               float* __restrict__ bmin, float* __restrict__ bmax) {
    __shared__ float smin[256], smax[256];
    int tid = threadIdx.x;
    int base = blockIdx.x * 256 + tid;
    float mn = 1e30f, mx = -1e30f;
#pragma unroll
    for (int k = 0; k < 24; ++k) {     // 64*256*24 = 393216 float4 = 1.57M floats
        float4 t4 = v[base + k * 16384];
        mn = fminf(mn, fminf(fminf(t4.x, t4.y), fminf(t4.z, t4.w)));
        mx = fmaxf(mx, fmaxf(fmaxf(t4.x, t4.y), fmaxf(t4.z, t4.w)));
    }
    smin[tid] = mn; smax[tid] = mx;
    __syncthreads();
    for (int s = 128; s > 0; s >>= 1) {
        if (tid < s) {
            smin[tid] = fminf(smin[tid], smin[tid + s]);
            smax[tid] = fmaxf(smax[tid], smax[tid + s]);
        }
        __syncthreads();
    }
    if (tid == 0) { bmin[blockIdx.x] = smin[0]; bmax[blockIdx.x] = smax[0]; }
}

// ---------------------------------------------------------------------------
// K2: windowed KDE entropy — SINGLE-WAVE blocks (64 threads, 2048 blocks).
//   All barriers are single-wave (compiler elides s_barrier; s_waitcnt only),
//   no inter-wave partial staging, butterfly shuffles leave vmin/vmax and the
//   pdf sums in every lane. Each lane owns 12 values (coalesced loads,
//   count + scatter atomics) and one full bin window in bucket order.
//   Window reads stay scalar ds_read_b32 (R6: b128 = 8-way conflicts).
// ---------------------------------------------------------------------------
__global__ __launch_bounds__(64) void entropy_kernel(
    const float* __restrict__ img,
    const float* __restrict__ bmin,
    const float* __restrict__ bmax,
    float* __restrict__ ent) {
    __shared__ float snv[PB];        // bucket-sorted normalized values
    __shared__ int   cnt[NBINS];     // bucket counts
    __shared__ int   bs[NBINS + 1];  // bucket start offsets (exclusive scan)
    __shared__ int   pos[NBINS];     // running scatter cursors

    int t = blockIdx.x;              // token 0..2047
    int lane = threadIdx.x;          // 0..63 = bin

    // ---- reduce 64 partials -> vmin/vmax (butterfly: result in all lanes) ----
    float vmin = bmin[lane], vmax = bmax[lane];
    for (int m = 1; m < 64; m <<= 1) {
        vmin = fminf(vmin, __shfl_xor(vmin, m, 64));
        vmax = fmaxf(vmax, __shfl_xor(vmax, m, 64));
    }
    float inv = 1.0f / (vmax - vmin);

    cnt[lane] = 0;
    __syncthreads();

    // ---- load my 12 values, normalize, count buckets ----
    const float* row = img + (size_t)t * PB;
    float nv[12];
    int   mb[12];
#pragma unroll
    for (int k = 0; k < 12; ++k) {
        nv[k] = (row[lane + 64 * k] - vmin) * inv;
        mb[k] = min(63, max(0, __float2int_rn(nv[k] * 63.0f)));
        atomicAdd(&cnt[mb[k]], 1);
    }
    __syncthreads();

    // ---- exclusive scan of bucket counts (wave-wide shuffle scan) ----
    {
        int c = cnt[lane];
        int incl = c;
        for (int off = 1; off < 64; off <<= 1) {
            int up = __shfl_up(incl, off, 64);
            if (lane >= off) incl += up;
        }
        bs[lane + 1] = incl;
        pos[lane] = incl - c;        // exclusive prefix
        if (lane == 0) bs[0] = 0;
    }
    __syncthreads();

    // ---- scatter values into bucket-sorted order ----
#pragma unroll
    for (int k = 0; k < 12; ++k)
        snv[atomicAdd(&pos[mb[k]], 1)] = nv[k];
    __syncthreads();

    // ---- windowed accumulation: lane = bin, full window serial ----
    float bv = (float)lane * (1.0f / 63.0f);
    int lo = bs[max(0, lane - WIN)];
    int hi = bs[min(NBINS, lane + WIN + 1)];
    const float negC = -7213.4755859375f;   // -(5000 * log2 e)
    float acc = 0.0f;
    for (int j = lo; j < hi; ++j) {
        float d = snv[j] - bv;
        acc += fast_exp2(d * d * negC);
    }

    // ---- finish: pdf normalize + entropy (all in-wave) ----
    float pdf = acc * (1.0f / (float)PB);
    float s = pdf;
    for (int m = 1; m < 64; m <<= 1) s += __shfl_xor(s, m, 64);
    float p = pdf / (s + EPSL) + EPSL;
    float term = p * __logf(p);
    for (int m = 1; m < 64; m <<= 1) term += __shfl_xor(term, m, 64);
    if (lane == 0) ent[t] = -term;
}

// ---------------------------------------------------------------------------
// K3: fused stable-rank + self-owned gather. 128 blocks x 256 threads.
//   Block b handles row n = b>>5, elements i in [(b&31)*16, +16).
//   16 threads/element: thread slice = tid&15 scans 32 j's; 4-step shfl_xor
//   combine (16-lane groups are wave-internal). Zero redundant rank work.
//   Each block gathers ONLY the x rows it ranked kept (avg 4, max 16).
// ---------------------------------------------------------------------------
__global__ void rank_gather_kernel(const float* __restrict__ x,
                                   const float* __restrict__ ent,
                                   float* __restrict__ out_x,
                                   float* __restrict__ out_mask,
                                   float* __restrict__ out_rest) {
    __shared__ float sh[LB];
    __shared__ int keep_list[16];    // (slot<<16) | row_idx
    __shared__ int nkeep;
    int b = blockIdx.x, tid = threadIdx.x;
    int n = b >> 5;                       // row 0..3 (uniform per block)
    int i = (b & 31) * 16 + (tid >> 4);   // element in row (16 per block)
    int slice = tid & 15;                 // j-slice

    if (tid == 0) nkeep = 0;
    sh[tid]       = ent[n * LB + tid];
    sh[256 + tid] = ent[n * LB + 256 + tid];
    __syncthreads();

    unsigned long long ci =
        ((unsigned long long)__float_as_uint(sh[i]) << 32) | (unsigned int)i;
    int r = 0;
    int j0 = slice * 32;
#pragma unroll 8
    for (int j = j0; j < j0 + 32; ++j) {      // LDS broadcast reads
        unsigned long long cj =
            ((unsigned long long)__float_as_uint(sh[j]) << 32) | (unsigned int)j;
        r += (cj < ci) ? 1 : 0;
    }
    r += __shfl_xor(r, 1, 64);
    r += __shfl_xor(r, 2, 64);
    r += __shfl_xor(r, 4, 64);
    r += __shfl_xor(r, 8, 64);                // full rank in all 16 lanes
    if (slice == 0) {
        out_rest[n * LB + i] = (float)r;
        out_mask[n * LB + i] = (r < LEN_KEEP) ? 0.0f : 1.0f;
        if (r < LEN_KEEP) {
            int e = atomicAdd(&nkeep, 1);
            keep_list[e] = (r << 16) | i;
        }
    }
    __syncthreads();

    int nk = nkeep;
    for (int e = 0; e < nk; ++e) {
        int ent_ri = keep_list[e];
        int slot = ent_ri >> 16;
        int rowi = ent_ri & 0xFFFF;
        const float4* src = (const float4*)(x + ((size_t)(n * LB + rowi)) * DB);
        float4* dst = (float4*)(out_x + ((size_t)(n * LEN_KEEP + slot)) * DB);
        dst[tid] = src[tid];     // 256 threads x 16B = one full 4KB row
    }
}

extern "C" void kernel_launch(void* const* d_in, const int* in_sizes, int n_in,
                              void* d_out, int out_size, void* d_ws, size_t ws_size,
                              hipStream_t stream) {
    const float* x   = (const float*)d_in[0];   // (4,512,1024)
    const float* img = (const float*)d_in[1];   // (4,512,768)

    float* out      = (float*)d_out;
    float* out_x    = out;                               // 4*128*1024
    float* out_mask = out + (size_t)NB * LEN_KEEP * DB;  // 4*512
    float* out_rest = out_mask + NB * LB;                // 4*512

    float* ws   = (float*)d_ws;
    float* bmin = ws;            // 64
    float* bmax = ws + 64;       // 64
    float* ent  = ws + 128;      // 2048

    minmax_partial<<<64, 256, 0, stream>>>((const float4*)img, bmin, bmax);
    entropy_kernel<<<NB * LB, 64, 0, stream>>>(img, bmin, bmax, ent);
    rank_gather_kernel<<<128, 256, 0, stream>>>(x, ent, out_x, out_mask, out_rest);
}

// Round 12
// 75.128 us; speedup vs baseline: 1.0744x; 1.0744x over previous
//
#include <hip/hip_runtime.h>

#define NB 4
#define LB 512
#define DB 1024
#define PB 768
#define NBINS 64
#define LEN_KEEP 128          // int(512 * (1 - 0.75))
#define EPSL 1e-19f
#define WIN 3                 // excluded buckets are >=3.5 spacings away:
                              // kern <= 2^-22.3 ~ 2e-7; dropped mass ~1e-5
                              // vs per-bin sums O(10) -> ~1e-6 relative

#if defined(__has_builtin)
#if __has_builtin(__builtin_amdgcn_exp2f)
#define HAVE_EXP2 1
#endif
#endif

__device__ __forceinline__ float fast_exp2(float x) {
#ifdef HAVE_EXP2
    return __builtin_amdgcn_exp2f(x);   // raw v_exp_f32
#else
    return __expf(x * 0.69314718055994530942f);
#endif
}

// ---------------------------------------------------------------------------
// K1: min/max partials over img, 64 blocks x 256 threads, float4 loads.
//     64 partials -> entropy prologue reduces them with one wave-shuffle.
// ---------------------------------------------------------------------------
__global__ void minmax_partial(const float4* __restrict__ v,
                               float* __restrict__ bmin, float* __restrict__ bmax) {
    __shared__ float smin[256], smax[256];
    int tid = threadIdx.x;
    int base = blockIdx.x * 256 + tid;
    float mn = 1e30f, mx = -1e30f;
#pragma unroll
    for (int k = 0; k < 24; ++k) {     // 64*256*24 = 393216 float4 = 1.57M floats
        float4 t4 = v[base + k * 16384];
        mn = fminf(mn, fminf(fminf(t4.x, t4.y), fminf(t4.z, t4.w)));
        mx = fmaxf(mx, fmaxf(fmaxf(t4.x, t4.y), fmaxf(t4.z, t4.w)));
    }
    smin[tid] = mn; smax[tid] = mx;
    __syncthreads();
    for (int s = 128; s > 0; s >>= 1) {
        if (tid < s) {
            smin[tid] = fminf(smin[tid], smin[tid + s]);
            smax[tid] = fmaxf(smax[tid], smax[tid + s]);
        }
        __syncthreads();
    }
    if (tid == 0) { bmin[blockIdx.x] = smin[0]; bmax[blockIdx.x] = smax[0]; }
}

// ---------------------------------------------------------------------------
// K2: windowed KDE entropy, one block per token (256 threads = 4 waves).
//   prologue: wave 0 shuffle-reduces the 64 min/max partials.
//   counting-sort the 768 normalized values into 64 LDS buckets, then each
//   lane (= bin b) sums exp2(-7213.476*d^2) over buckets [b-WIN, b+WIN],
//   window split stride-4 across the 4 waves (TLP > barrier-count: R11).
//   Window reads are scalar ds_read_b32 (R6: b128 here = 8-way conflicts).
// ---------------------------------------------------------------------------
__global__ void entropy_kernel(const float* __restrict__ img,
                               const float* __restrict__ bmin,
                               const float* __restrict__ bmax,
                               float* __restrict__ ent) {
    __shared__ float sh[256];        // vmin/vmax bcast, then wave bin partials
    __shared__ float snv[PB];        // bucket-sorted normalized values
    __shared__ int   cnt[NBINS];     // bucket counts
    __shared__ int   bs[NBINS + 1];  // bucket start offsets (exclusive scan)
    __shared__ int   pos[NBINS];     // running scatter cursors

    int t = blockIdx.x;              // token 0..2047
    int tid = threadIdx.x;
    int lane = tid & 63;
    int w = tid >> 6;

    if (tid < NBINS) cnt[tid] = 0;
    // ---- reduce 64 partials -> vmin/vmax (wave 0) ----
    if (tid < 64) {
        float mn = bmin[tid], mx = bmax[tid];
        for (int m = 1; m < 64; m <<= 1) {
            mn = fminf(mn, __shfl_xor(mn, m, 64));
            mx = fmaxf(mx, __shfl_xor(mx, m, 64));
        }
        if (tid == 0) { sh[0] = mn; sh[1] = mx; }
    }
    __syncthreads();
    float vmin = sh[0], vmax = sh[1];
    float inv = 1.0f / (vmax - vmin);

    // ---- load my 3 values, normalize, count buckets ----
    const float* row = img + (size_t)t * PB;
    float nv0 = (row[tid]       - vmin) * inv;
    float nv1 = (row[tid + 256] - vmin) * inv;
    float nv2 = (row[tid + 512] - vmin) * inv;
    int m0 = min(63, max(0, __float2int_rn(nv0 * 63.0f)));
    int m1 = min(63, max(0, __float2int_rn(nv1 * 63.0f)));
    int m2 = min(63, max(0, __float2int_rn(nv2 * 63.0f)));
    atomicAdd(&cnt[m0], 1);
    atomicAdd(&cnt[m1], 1);
    atomicAdd(&cnt[m2], 1);
    __syncthreads();

    // ---- exclusive scan of bucket counts (one wave) ----
    if (tid < 64) {
        int c = cnt[tid];
        int incl = c;
        for (int off = 1; off < 64; off <<= 1) {
            int up = __shfl_up(incl, off, 64);
            if (tid >= off) incl += up;
        }
        bs[tid + 1] = incl;
        pos[tid] = incl - c;       // exclusive prefix
        if (tid == 0) bs[0] = 0;
    }
    __syncthreads();

    // ---- scatter values into bucket-sorted order ----
    snv[atomicAdd(&pos[m0], 1)] = nv0;
    snv[atomicAdd(&pos[m1], 1)] = nv1;
    snv[atomicAdd(&pos[m2], 1)] = nv2;
    __syncthreads();

    // ---- windowed accumulation: lane = bin, 4 waves take stride-4 slices ----
    float bv = (float)lane * (1.0f / 63.0f);
    int lo = bs[max(0, lane - WIN)];
    int hi = bs[min(NBINS, lane + WIN + 1)];
    const float negC = -7213.4755859375f;   // -(5000 * log2 e)
    float acc = 0.0f;
    for (int j = lo + w; j < hi; j += 4) {
        float d = snv[j] - bv;
        acc += fast_exp2(d * d * negC);
    }
    sh[w * NBINS + lane] = acc;
    __syncthreads();

    // ---- finish: pdf normalize + entropy (one wavefront) ----
    if (tid < 64) {
        float pdf = (sh[lane] + sh[64 + lane] + sh[128 + lane] + sh[192 + lane])
                    * (1.0f / (float)PB);
        float s = pdf;
        for (int m = 1; m < 64; m <<= 1) s += __shfl_xor(s, m, 64);
        float p = pdf / (s + EPSL) + EPSL;
        float term = p * __logf(p);
        for (int m = 1; m < 64; m <<= 1) term += __shfl_xor(term, m, 64);
        if (tid == 0) ent[t] = -term;
    }
}

// ---------------------------------------------------------------------------
// K3: fused stable-rank + self-owned gather. 128 blocks x 256 threads.
//   Block b handles row n = b>>5, elements i in [(b&31)*16, +16).
//   16 threads/element: thread slice = tid&15 scans 32 j's; 4-step shfl_xor
//   combine (16-lane groups are wave-internal). Zero redundant rank work
//   (R4/R7 lesson). Each block gathers ONLY the x rows it ranked kept
//   (avg 4, max 16) via an LDS-compacted (slot,row) list.
// ---------------------------------------------------------------------------
__global__ void rank_gather_kernel(const float* __restrict__ x,
                                   const float* __restrict__ ent,
                                   float* __restrict__ out_x,
                                   float* __restrict__ out_mask,
                                   float* __restrict__ out_rest) {
    __shared__ float sh[LB];
    __shared__ int keep_list[16];    // (slot<<16) | row_idx
    __shared__ int nkeep;
    int b = blockIdx.x, tid = threadIdx.x;
    int n = b >> 5;                       // row 0..3 (uniform per block)
    int i = (b & 31) * 16 + (tid >> 4);   // element in row (16 per block)
    int slice = tid & 15;                 // j-slice

    if (tid == 0) nkeep = 0;
    sh[tid]       = ent[n * LB + tid];
    sh[256 + tid] = ent[n * LB + 256 + tid];
    __syncthreads();

    unsigned long long ci =
        ((unsigned long long)__float_as_uint(sh[i]) << 32) | (unsigned int)i;
    int r = 0;
    int j0 = slice * 32;
#pragma unroll 8
    for (int j = j0; j < j0 + 32; ++j) {      // LDS broadcast reads
        unsigned long long cj =
            ((unsigned long long)__float_as_uint(sh[j]) << 32) | (unsigned int)j;
        r += (cj < ci) ? 1 : 0;
    }
    r += __shfl_xor(r, 1, 64);
    r += __shfl_xor(r, 2, 64);
    r += __shfl_xor(r, 4, 64);
    r += __shfl_xor(r, 8, 64);                // full rank in all 16 lanes
    if (slice == 0) {
        out_rest[n * LB + i] = (float)r;
        out_mask[n * LB + i] = (r < LEN_KEEP) ? 0.0f : 1.0f;
        if (r < LEN_KEEP) {
            int e = atomicAdd(&nkeep, 1);
            keep_list[e] = (r << 16) | i;
        }
    }
    __syncthreads();

    int nk = nkeep;
    for (int e = 0; e < nk; ++e) {
        int ent_ri = keep_list[e];
        int slot = ent_ri >> 16;
        int rowi = ent_ri & 0xFFFF;
        const float4* src = (const float4*)(x + ((size_t)(n * LB + rowi)) * DB);
        float4* dst = (float4*)(out_x + ((size_t)(n * LEN_KEEP + slot)) * DB);
        dst[tid] = src[tid];     // 256 threads x 16B = one full 4KB row
    }
}

extern "C" void kernel_launch(void* const* d_in, const int* in_sizes, int n_in,
                              void* d_out, int out_size, void* d_ws, size_t ws_size,
                              hipStream_t stream) {
    const float* x   = (const float*)d_in[0];   // (4,512,1024)
    const float* img = (const float*)d_in[1];   // (4,512,768)

    float* out      = (float*)d_out;
    float* out_x    = out;                               // 4*128*1024
    float* out_mask = out + (size_t)NB * LEN_KEEP * DB;  // 4*512
    float* out_rest = out_mask + NB * LB;                // 4*512

    float* ws   = (float*)d_ws;
    float* bmin = ws;            // 64
    float* bmax = ws + 64;       // 64
    float* ent  = ws + 128;      // 2048

    minmax_partial<<<64, 256, 0, stream>>>((const float4*)img, bmin, bmax);
    entropy_kernel<<<NB * LB, 256, 0, stream>>>(img, bmin, bmax, ent);
    rank_gather_kernel<<<128, 256, 0, stream>>>(x, ent, out_x, out_mask, out_rest);
}